// Round 6
// baseline (766.971 us; speedup 1.0000x reference)
//
#include <hip/hip_runtime.h>
#include <hip/hip_bf16.h>
#include <cstddef>

#define B_ 4
#define S_ 1024
#define E_ 1024
#define H_ 16
#define D_ 64
#define BH_ (B_*H_)

typedef __attribute__((ext_vector_type(8))) short short8;    // 8 bf16
typedef __attribute__((ext_vector_type(4))) float f32x4;
typedef __attribute__((ext_vector_type(4))) unsigned short us4;
typedef unsigned short u16;

__device__ inline u16 f2b(float x) {
    return __builtin_bit_cast(u16, __float2bfloat16(x));
}
__device__ inline float b2f(u16 u) {
    return __bfloat162float(__builtin_bit_cast(__hip_bfloat16, u));
}
__device__ inline void splitf(float x, u16& h, u16& l) {
    h = f2b(x); l = f2b(x - b2f(h));
}

// ---------------------------------------------------------------------------
// split fp32 array into hi/lo bf16 arrays (n4 = n/4)
// ---------------------------------------------------------------------------
__global__ __launch_bounds__(256) void split_pair(
    const float* __restrict__ in, u16* __restrict__ oh, u16* __restrict__ ol, int n4)
{
    int i = blockIdx.x * 256 + threadIdx.x;
    if (i >= n4) return;
    float4 v = ((const float4*)in)[i];
    us4 h, l;
    splitf(v.x, ((u16*)&h)[0], ((u16*)&l)[0]);
    splitf(v.y, ((u16*)&h)[1], ((u16*)&l)[1]);
    splitf(v.z, ((u16*)&h)[2], ((u16*)&l)[2]);
    splitf(v.w, ((u16*)&h)[3], ((u16*)&l)[3]);
    ((us4*)oh)[i] = h;
    ((us4*)ol)[i] = l;
}

// xsum[b][k] = sum_s x[b,s,k]
__global__ __launch_bounds__(256) void reduce_xsum(
    const float* __restrict__ x, float* __restrict__ xsum)
{
    int b = blockIdx.y;
    int k = blockIdx.x * 256 + threadIdx.x;
    float s = 0.f;
    const float* base = x + (size_t)b * S_ * E_ + k;
    for (int j = 0; j < S_; ++j) s += base[(size_t)j * E_];
    xsum[b * E_ + k] = s;
}

// t2n[b][n] = dot(W2[n], xsum[b]) + S*b2[n]
__global__ __launch_bounds__(256) void compute_t2k(
    const float* __restrict__ W2, const float* __restrict__ b2,
    const float* __restrict__ xsum, float* __restrict__ t2n)
{
    int b = blockIdx.y, n0 = blockIdx.x * 64;
    int w = threadIdx.x >> 6, lane = threadIdx.x & 63;
    const float* xs = xsum + b * E_;
    for (int nn = w; nn < 64; nn += 4) {
        int n = n0 + nn;
        const float* wr = W2 + (size_t)n * E_;
        float s = 0.f;
#pragma unroll
        for (int t = 0; t < 16; ++t) s = fmaf(wr[t * 64 + lane], xs[t * 64 + lane], s);
#pragma unroll
        for (int off = 1; off < 64; off <<= 1) s += __shfl_xor(s, off, 64);
        if (lane == 0) t2n[b * E_ + n] = s + 1024.0f * b2[n];
    }
}

// M[bh][a][c] = (1/8) * sum_d A[a][c][d] * t2[bh][d]
__global__ void compute_M(const float* __restrict__ A, const float* __restrict__ t2n,
                          float* __restrict__ Mout)
{
    int bh = blockIdx.x, b = bh >> 4, h = bh & 15;
    __shared__ float ts[64];
    if (threadIdx.x < 64) ts[threadIdx.x] = t2n[b * E_ + h * 64 + threadIdx.x];
    __syncthreads();
    int c = threadIdx.x & 63;
    int a0 = (threadIdx.x >> 6) * 16;
    for (int a = a0; a < a0 + 16; ++a) {
        float s = 0.f;
        const float* Ap = A + ((size_t)a * 64 + c) * 64;
#pragma unroll 8
        for (int d = 0; d < 64; ++d) s = fmaf(Ap[d], ts[d], s);
        Mout[((size_t)bh * 64 + a) * 64 + c] = s * 0.125f;
    }
}

// ---------------------------------------------------------------------------
// split-bf16 GEMM (round-4 structure): C = X*W^T + bias, 64x64 tile.
// mode 0: write fp32 heads layout (p0)
// mode 1: write hi/lo bf16 heads layout (p1)
// ---------------------------------------------------------------------------
__global__ __launch_bounds__(256) void gemm_split(
    const u16* __restrict__ Xh, const u16* __restrict__ Xl,
    const u16* __restrict__ Wh, const u16* __restrict__ Wl,
    const float* __restrict__ bias, float* __restrict__ outF,
    u16* __restrict__ oh, u16* __restrict__ ol, int mode)
{
    const int K = 1024;
    __shared__ __align__(16) u16 Xs_h[64 * 40];
    __shared__ __align__(16) u16 Xs_l[64 * 40];
    __shared__ __align__(16) u16 Ws_h[64 * 40];
    __shared__ __align__(16) u16 Ws_l[64 * 40];

    const int tid = threadIdx.x;
    const int w = tid >> 6, lane = tid & 63;
    const int waveM = w & 1, waveN = w >> 1;
    const int quad = lane >> 4, l16 = lane & 15;
    const int bm = blockIdx.x, bn = blockIdx.y;

    const int lrow = tid >> 2, lkoff = (tid & 3) * 8;
    const u16* xh_g = Xh + (size_t)(bm * 64 + lrow) * K + lkoff;
    const u16* xl_g = Xl + (size_t)(bm * 64 + lrow) * K + lkoff;
    const u16* wh_g = Wh + (size_t)(bn * 64 + lrow) * K + lkoff;
    const u16* wl_g = Wl + (size_t)(bn * 64 + lrow) * K + lkoff;

    f32x4 acc[2][2] = {};

    for (int k0 = 0; k0 < K; k0 += 32) {
        uint4 a = *(const uint4*)(xh_g + k0);
        uint4 b = *(const uint4*)(xl_g + k0);
        uint4 c = *(const uint4*)(wh_g + k0);
        uint4 d = *(const uint4*)(wl_g + k0);
        __syncthreads();
        *(uint4*)&Xs_h[lrow * 40 + lkoff] = a;
        *(uint4*)&Xs_l[lrow * 40 + lkoff] = b;
        *(uint4*)&Ws_h[lrow * 40 + lkoff] = c;
        *(uint4*)&Ws_l[lrow * 40 + lkoff] = d;
        __syncthreads();

        short8 ah[2], al[2], bh_[2], bl_[2];
#pragma unroll
        for (int mt = 0; mt < 2; ++mt) {
            int r = (waveM * 32 + mt * 16 + l16) * 40 + quad * 8;
            ah[mt] = *(short8*)&Xs_h[r];
            al[mt] = *(short8*)&Xs_l[r];
        }
#pragma unroll
        for (int nt = 0; nt < 2; ++nt) {
            int r = (waveN * 32 + nt * 16 + l16) * 40 + quad * 8;
            bh_[nt] = *(short8*)&Ws_h[r];
            bl_[nt] = *(short8*)&Ws_l[r];
        }
#pragma unroll
        for (int mt = 0; mt < 2; ++mt)
#pragma unroll
            for (int nt = 0; nt < 2; ++nt) {
                acc[mt][nt] = __builtin_amdgcn_mfma_f32_16x16x32_bf16(ah[mt], bh_[nt], acc[mt][nt], 0, 0, 0);
                acc[mt][nt] = __builtin_amdgcn_mfma_f32_16x16x32_bf16(ah[mt], bl_[nt], acc[mt][nt], 0, 0, 0);
                acc[mt][nt] = __builtin_amdgcn_mfma_f32_16x16x32_bf16(al[mt], bh_[nt], acc[mt][nt], 0, 0, 0);
            }
    }

#pragma unroll
    for (int mt = 0; mt < 2; ++mt)
#pragma unroll
        for (int nt = 0; nt < 2; ++nt)
#pragma unroll
            for (int r = 0; r < 4; ++r) {
                int m = bm * 64 + waveM * 32 + mt * 16 + quad * 4 + r;
                int n = bn * 64 + waveN * 32 + nt * 16 + l16;
                float val = acc[mt][nt][r] + bias[n];
                int b = m >> 10, s = m & 1023, h = n >> 6, c = n & 63;
                size_t addr = ((size_t)(b * H_ + h) * S_ + s) * 64 + c;
                if (mode == 0) {
                    outF[addr] = val;
                } else {
                    u16 hh, ll; splitf(val, hh, ll);
                    oh[addr] = hh; ol[addr] = ll;
                }
            }
}

// q[bh][i][c] = sum_a p0[bh][i][a] * M[bh][a][c]; write hi/lo bf16
__global__ __launch_bounds__(256) void compute_q(
    const float* __restrict__ p0, const float* __restrict__ Min,
    u16* __restrict__ qh, u16* __restrict__ ql)
{
    int bh = blockIdx.y, i0 = blockIdx.x * 16;
    __shared__ float Ms[64 * 68];
    __shared__ float p0s[16 * 64];
    const float* base = p0 + ((size_t)bh * S_ + i0) * 64;
    for (int t = threadIdx.x; t < 4096; t += 256)
        Ms[(t >> 6) * 68 + (t & 63)] = Min[(size_t)bh * 4096 + t];
    for (int t = threadIdx.x; t < 1024; t += 256) p0s[t] = base[t];
    __syncthreads();
    int c = threadIdx.x & 63, il = threadIdx.x >> 6;
#pragma unroll
    for (int rr = 0; rr < 4; ++rr) {
        int ilocal = rr * 4 + il;
        const float* p0r = &p0s[ilocal * 64];
        float s = 0.f;
#pragma unroll 8
        for (int a = 0; a < 64; ++a) s = fmaf(p0r[a], Ms[a * 68 + c], s);
        size_t addr = ((size_t)bh * S_ + i0 + ilocal) * 64 + c;
        u16 hh, ll; splitf(s, hh, ll);
        qh[addr] = hh; ql[addr] = ll;
    }
}

// ---------------------------------------------------------------------------
// plain bf16 GEMM 64x64: X bf16 natural * W fp32 (cvt in staging) + bias
// mode 0: out bf16 TRANSPOSED heads layout vT[(bh*64 + d)*S + s]   (v)
// mode 1: out fp32 natural                                          (final)
// ---------------------------------------------------------------------------
__global__ __launch_bounds__(256) void gemm_plain(
    const u16* __restrict__ Xb, const float* __restrict__ Wf,
    const float* __restrict__ bias, u16* __restrict__ outB,
    float* __restrict__ outF, int mode)
{
    const int K = 1024;
    __shared__ __align__(16) u16 Xs[64 * 40];
    __shared__ __align__(16) u16 Ws[64 * 40];

    const int tid = threadIdx.x;
    const int w = tid >> 6, lane = tid & 63;
    const int waveM = w & 1, waveN = w >> 1;
    const int quad = lane >> 4, l16 = lane & 15;
    const int bm = blockIdx.x, bn = blockIdx.y;
    const int lrow = tid >> 2, lkoff = (tid & 3) * 8;

    const u16* xg = Xb + (size_t)(bm * 64 + lrow) * K + lkoff;
    const float* wg = Wf + (size_t)(bn * 64 + lrow) * K + lkoff;

    f32x4 acc[2][2] = {};

    for (int k0 = 0; k0 < K; k0 += 32) {
        uint4 xv = *(const uint4*)(xg + k0);
        float4 w0 = *(const float4*)(wg + k0);
        float4 w1 = *(const float4*)(wg + k0 + 4);
        short8 wp;
        ((u16*)&wp)[0] = f2b(w0.x); ((u16*)&wp)[1] = f2b(w0.y);
        ((u16*)&wp)[2] = f2b(w0.z); ((u16*)&wp)[3] = f2b(w0.w);
        ((u16*)&wp)[4] = f2b(w1.x); ((u16*)&wp)[5] = f2b(w1.y);
        ((u16*)&wp)[6] = f2b(w1.z); ((u16*)&wp)[7] = f2b(w1.w);
        __syncthreads();
        *(uint4*)&Xs[lrow * 40 + lkoff] = xv;
        *(short8*)&Ws[lrow * 40 + lkoff] = wp;
        __syncthreads();

        short8 af[2], bf_[2];
#pragma unroll
        for (int mt = 0; mt < 2; ++mt)
            af[mt] = *(short8*)&Xs[(waveM * 32 + mt * 16 + l16) * 40 + quad * 8];
#pragma unroll
        for (int nt = 0; nt < 2; ++nt)
            bf_[nt] = *(short8*)&Ws[(waveN * 32 + nt * 16 + l16) * 40 + quad * 8];
#pragma unroll
        for (int mt = 0; mt < 2; ++mt)
#pragma unroll
            for (int nt = 0; nt < 2; ++nt)
                acc[mt][nt] = __builtin_amdgcn_mfma_f32_16x16x32_bf16(af[mt], bf_[nt], acc[mt][nt], 0, 0, 0);
    }

#pragma unroll
    for (int mt = 0; mt < 2; ++mt)
#pragma unroll
        for (int nt = 0; nt < 2; ++nt)
#pragma unroll
            for (int r = 0; r < 4; ++r) {
                int m = bm * 64 + waveM * 32 + mt * 16 + quad * 4 + r;
                int n = bn * 64 + waveN * 32 + nt * 16 + l16;
                float val = acc[mt][nt][r] + bias[n];
                if (mode == 0) {
                    int b = m >> 10, s = m & 1023, h = n >> 6, c = n & 63;
                    outB[((size_t)((b * H_ + h) * 64 + c)) * S_ + s] = f2b(val);
                } else {
                    outF[(size_t)m * 1024 + n] = val;
                }
            }
}

// ---------------------------------------------------------------------------
// logits = q*p1^T (split-bf16 MFMA), softmax over j, write fp32 attn.
// (round-4 code, verbatim — PASSING)
// ---------------------------------------------------------------------------
__global__ __launch_bounds__(256) void logits_softmax_mfma(
    const u16* __restrict__ qh, const u16* __restrict__ ql,
    const u16* __restrict__ p1h, const u16* __restrict__ p1l,
    float* __restrict__ attn)
{
    int bh = blockIdx.y, i0 = blockIdx.x * 16;
    int tid = threadIdx.x, w = tid >> 6, lane = tid & 63;
    int quad = lane >> 4, l16 = lane & 15;

    __shared__ __align__(16) u16 qhs[16 * 72], qls[16 * 72];
    __shared__ __align__(16) u16 p1hs[64 * 72], p1ls[64 * 72];
    __shared__ float redm[4][16], reds[4][16];

    {   // stage q (16x64 hi/lo)
        int row = tid >> 4, c0 = (tid & 15) * 4;
        size_t g = ((size_t)bh * S_ + i0 + row) * 64 + c0;
        *(us4*)&qhs[row * 72 + c0] = *(const us4*)&qh[g];
        *(us4*)&qls[row * 72 + c0] = *(const us4*)&ql[g];
    }
    __syncthreads();

    short8 ah[2], al[2];
#pragma unroll
    for (int ch = 0; ch < 2; ++ch) {
        ah[ch] = *(short8*)&qhs[l16 * 72 + ch * 32 + quad * 8];
        al[ch] = *(short8*)&qls[l16 * 72 + ch * 32 + quad * 8];
    }

    f32x4 L[16];
    for (int t = 0; t < 16; ++t) {
        __syncthreads();
        {   // stage p1 rows t*64 .. t*64+63 (hi/lo)
            int jl = tid >> 2, c0 = (tid & 3) * 16;
            size_t g = ((size_t)bh * S_ + t * 64 + jl) * 64 + c0;
            *(uint4*)&p1hs[jl * 72 + c0]     = *(const uint4*)&p1h[g];
            *(uint4*)&p1hs[jl * 72 + c0 + 8] = *(const uint4*)&p1h[g + 8];
            *(uint4*)&p1ls[jl * 72 + c0]     = *(const uint4*)&p1l[g];
            *(uint4*)&p1ls[jl * 72 + c0 + 8] = *(const uint4*)&p1l[g + 8];
        }
        __syncthreads();
        int jr = w * 16 + l16;
        short8 bh0 = *(short8*)&p1hs[jr * 72 + quad * 8];
        short8 bh1 = *(short8*)&p1hs[jr * 72 + 32 + quad * 8];
        short8 bl0 = *(short8*)&p1ls[jr * 72 + quad * 8];
        short8 bl1 = *(short8*)&p1ls[jr * 72 + 32 + quad * 8];
        f32x4 a = {};
        a = __builtin_amdgcn_mfma_f32_16x16x32_bf16(ah[0], bh0, a, 0, 0, 0);
        a = __builtin_amdgcn_mfma_f32_16x16x32_bf16(ah[1], bh1, a, 0, 0, 0);
        a = __builtin_amdgcn_mfma_f32_16x16x32_bf16(ah[0], bl0, a, 0, 0, 0);
        a = __builtin_amdgcn_mfma_f32_16x16x32_bf16(ah[1], bl1, a, 0, 0, 0);
        a = __builtin_amdgcn_mfma_f32_16x16x32_bf16(al[0], bh0, a, 0, 0, 0);
        a = __builtin_amdgcn_mfma_f32_16x16x32_bf16(al[1], bh1, a, 0, 0, 0);
        L[t] = a;
    }

    float mrow[4], srow[4];
#pragma unroll
    for (int r = 0; r < 4; ++r) {
        float m = L[0][r];
#pragma unroll
        for (int t = 1; t < 16; ++t) m = fmaxf(m, L[t][r]);
#pragma unroll
        for (int off = 1; off < 16; off <<= 1) m = fmaxf(m, __shfl_xor(m, off, 64));
        mrow[r] = m;
    }
    if (l16 == 0)
#pragma unroll
        for (int r = 0; r < 4; ++r) redm[w][quad * 4 + r] = mrow[r];
    __syncthreads();
#pragma unroll
    for (int r = 0; r < 4; ++r) {
        int row = quad * 4 + r;
        float m = fmaxf(fmaxf(redm[0][row], redm[1][row]), fmaxf(redm[2][row], redm[3][row]));
        float s = 0.f;
#pragma unroll
        for (int t = 0; t < 16; ++t) { L[t][r] = __expf(L[t][r] - m); s += L[t][r]; }
#pragma unroll
        for (int off = 1; off < 16; off <<= 1) s += __shfl_xor(s, off, 64);
        srow[r] = s;
    }
    if (l16 == 0)
#pragma unroll
        for (int r = 0; r < 4; ++r) reds[w][quad * 4 + r] = srow[r];
    __syncthreads();
#pragma unroll
    for (int r = 0; r < 4; ++r) {
        int row = quad * 4 + r;
        float inv = 1.0f / (reds[0][row] + reds[1][row] + reds[2][row] + reds[3][row]);
        float* arow = attn + ((size_t)bh * S_ + i0 + row) * S_;
#pragma unroll
        for (int t = 0; t < 16; ++t)
            arow[t * 64 + w * 16 + l16] = L[t][r] * inv;
    }
}

// ---------------------------------------------------------------------------
// values = attn @ v via MFMA. attn fp32 -> bf16 in staging; v read directly
// as bf16 from vT[(bh*64+d)*S + s] (B-operand rows, no transpose needed).
// Block: 64 i-rows of one bh; wave w owns i-group w*16..w*16+15.
// ---------------------------------------------------------------------------
__global__ __launch_bounds__(256) void attn_v_mfma(
    const float* __restrict__ attn, const u16* __restrict__ vT,
    u16* __restrict__ values)
{
    int bh = blockIdx.y, b = bh >> 4, h = bh & 15;
    int i0 = blockIdx.x * 64;
    int tid = threadIdx.x, w = tid >> 6, lane = tid & 63;
    int quad = lane >> 4, l16 = lane & 15;

    __shared__ __align__(16) u16 as_[64 * 72];
    __shared__ __align__(16) u16 vs_[64 * 72];
    f32x4 acc[4] = {};

    for (int j0 = 0; j0 < S_; j0 += 64) {
        __syncthreads();
        {   // attn tile 64x64 fp32 -> bf16 LDS
            int row = tid >> 2, c0 = (tid & 3) * 16;
            const float* src = attn + ((size_t)bh * S_ + i0 + row) * S_ + j0 + c0;
            float4 a0 = *(const float4*)&src[0];
            float4 a1 = *(const float4*)&src[4];
            float4 a2 = *(const float4*)&src[8];
            float4 a3 = *(const float4*)&src[12];
            short8 pA, pB;
            ((u16*)&pA)[0] = f2b(a0.x); ((u16*)&pA)[1] = f2b(a0.y);
            ((u16*)&pA)[2] = f2b(a0.z); ((u16*)&pA)[3] = f2b(a0.w);
            ((u16*)&pA)[4] = f2b(a1.x); ((u16*)&pA)[5] = f2b(a1.y);
            ((u16*)&pA)[6] = f2b(a1.z); ((u16*)&pA)[7] = f2b(a1.w);
            ((u16*)&pB)[0] = f2b(a2.x); ((u16*)&pB)[1] = f2b(a2.y);
            ((u16*)&pB)[2] = f2b(a2.z); ((u16*)&pB)[3] = f2b(a2.w);
            ((u16*)&pB)[4] = f2b(a3.x); ((u16*)&pB)[5] = f2b(a3.y);
            ((u16*)&pB)[6] = f2b(a3.z); ((u16*)&pB)[7] = f2b(a3.w);
            *(short8*)&as_[row * 72 + c0]     = pA;
            *(short8*)&as_[row * 72 + c0 + 8] = pB;
        }
        {   // v tile: vs_[d][j] direct bf16 copy from vT
            int d = tid >> 2, jc = (tid & 3) * 16;
            size_t g = ((size_t)(bh * 64 + d)) * S_ + j0 + jc;
            *(uint4*)&vs_[d * 72 + jc]     = *(const uint4*)&vT[g];
            *(uint4*)&vs_[d * 72 + jc + 8] = *(const uint4*)&vT[g + 8];
        }
        __syncthreads();
#pragma unroll
        for (int c0 = 0; c0 < 64; c0 += 32) {
            short8 af = *(short8*)&as_[(w * 16 + l16) * 72 + c0 + quad * 8];
#pragma unroll
            for (int dt = 0; dt < 4; ++dt) {
                short8 bf = *(short8*)&vs_[(dt * 16 + l16) * 72 + c0 + quad * 8];
                acc[dt] = __builtin_amdgcn_mfma_f32_16x16x32_bf16(af, bf, acc[dt], 0, 0, 0);
            }
        }
    }
#pragma unroll
    for (int dt = 0; dt < 4; ++dt)
#pragma unroll
        for (int r = 0; r < 4; ++r) {
            int i = i0 + w * 16 + quad * 4 + r;
            int d = dt * 16 + l16;
            values[((size_t)(b * S_ + i)) * E_ + h * 64 + d] = f2b(acc[dt][r]);
        }
}

extern "C" void kernel_launch(void* const* d_in, const int* in_sizes, int n_in,
                              void* d_out, int out_size, void* d_ws, size_t ws_size,
                              hipStream_t stream)
{
    const float* x  = (const float*)d_in[0];
    const float* W0 = (const float*)d_in[1];
    const float* b0 = (const float*)d_in[2];
    const float* W1 = (const float*)d_in[3];
    const float* b1 = (const float*)d_in[4];
    const float* W2 = (const float*)d_in[5];
    const float* b2 = (const float*)d_in[6];
    const float* Wv = (const float*)d_in[7];
    const float* bv = (const float*)d_in[8];
    const float* Wo = (const float*)d_in[9];
    const float* bo = (const float*)d_in[10];
    const float* A  = (const float*)d_in[11];

    float* out  = (float*)d_out;
    float* attn = out + (size_t)B_ * S_ * E_;

    // workspace (~88 MB; harness fill counters show d_ws >= 1 GB)
    u16* xh  = (u16*)d_ws;                  // 8 MB
    u16* xl  = xh + 4194304;                // 8 MB
    u16* w0h = xl + 4194304;                // 2 MB
    u16* w0l = w0h + 1048576;
    u16* w1h = w0l + 1048576;
    u16* w1l = w1h + 1048576;
    u16* p1h = w1l + 1048576;               // 8 MB
    u16* p1l = p1h + 4194304;               // 8 MB
    u16* qh  = p1l + 4194304;               // 8 MB
    u16* ql  = qh + 4194304;                // 8 MB
    u16* vT  = ql + 4194304;                // 8 MB (heads-transposed v)
    u16* values = vT + 4194304;             // 8 MB (bf16 natural)
    float* p0F  = (float*)(values + 4194304);  // 16 MB fp32 heads
    float* xsum = p0F + 4194304;            // 4096
    float* t2n  = xsum + 4096;              // 4096
    float* Mm   = t2n + 4096;               // 262144

    split_pair<<<4096, 256, 0, stream>>>(x, xh, xl, 1048576);
    split_pair<<<1024, 256, 0, stream>>>(W0, w0h, w0l, 262144);
    split_pair<<<1024, 256, 0, stream>>>(W1, w1h, w1l, 262144);
    reduce_xsum<<<dim3(4, 4), 256, 0, stream>>>(x, xsum);
    compute_t2k<<<dim3(16, 4), 256, 0, stream>>>(W2, b2, xsum, t2n);
    compute_M<<<BH_, 256, 0, stream>>>(A, t2n, Mm);

    dim3 gg(64, 16);
    gemm_split<<<gg, 256, 0, stream>>>(xh, xl, w0h, w0l, b0, p0F, nullptr, nullptr, 0);  // p0
    gemm_split<<<gg, 256, 0, stream>>>(xh, xl, w1h, w1l, b1, nullptr, p1h, p1l, 1);      // p1
    gemm_plain<<<gg, 256, 0, stream>>>(xh, Wv, bv, vT, nullptr, 0);                      // vT

    compute_q<<<dim3(64, 64), 256, 0, stream>>>(p0F, Mm, qh, ql);

    logits_softmax_mfma<<<dim3(64, 64), 256, 0, stream>>>(qh, ql, p1h, p1l, attn);
    attn_v_mfma<<<dim3(16, 64), 256, 0, stream>>>(attn, vT, values);

    gemm_plain<<<gg, 256, 0, stream>>>(values, Wo, bo, nullptr, out, 1);
}

// Round 7
// 761.205 us; speedup vs baseline: 1.0076x; 1.0076x over previous
//
#include <hip/hip_runtime.h>
#include <hip/hip_bf16.h>
#include <cstddef>

#define B_ 4
#define S_ 1024
#define E_ 1024
#define H_ 16
#define D_ 64
#define BH_ (B_*H_)

typedef __attribute__((ext_vector_type(8))) short short8;    // 8 bf16
typedef __attribute__((ext_vector_type(4))) float f32x4;
typedef __attribute__((ext_vector_type(4))) unsigned short us4;
typedef unsigned short u16;

__device__ inline u16 f2b(float x) {
    return __builtin_bit_cast(u16, __float2bfloat16(x));
}
__device__ inline float b2f(u16 u) {
    return __bfloat162float(__builtin_bit_cast(__hip_bfloat16, u));
}
__device__ inline void splitf(float x, u16& h, u16& l) {
    h = f2b(x); l = f2b(x - b2f(h));
}

// ---------------------------------------------------------------------------
// split fp32 array into hi/lo bf16 arrays (n4 = n/4)
// ---------------------------------------------------------------------------
__global__ __launch_bounds__(256) void split_pair(
    const float* __restrict__ in, u16* __restrict__ oh, u16* __restrict__ ol, int n4)
{
    int i = blockIdx.x * 256 + threadIdx.x;
    if (i >= n4) return;
    float4 v = ((const float4*)in)[i];
    us4 h, l;
    splitf(v.x, ((u16*)&h)[0], ((u16*)&l)[0]);
    splitf(v.y, ((u16*)&h)[1], ((u16*)&l)[1]);
    splitf(v.z, ((u16*)&h)[2], ((u16*)&l)[2]);
    splitf(v.w, ((u16*)&h)[3], ((u16*)&l)[3]);
    ((us4*)oh)[i] = h;
    ((us4*)ol)[i] = l;
}

// xsum[b][k] = sum_s x[b,s,k]
__global__ __launch_bounds__(256) void reduce_xsum(
    const float* __restrict__ x, float* __restrict__ xsum)
{
    int b = blockIdx.y;
    int k = blockIdx.x * 256 + threadIdx.x;
    float s = 0.f;
    const float* base = x + (size_t)b * S_ * E_ + k;
    for (int j = 0; j < S_; ++j) s += base[(size_t)j * E_];
    xsum[b * E_ + k] = s;
}

// t2n[b][n] = dot(W2[n], xsum[b]) + S*b2[n]
__global__ __launch_bounds__(256) void compute_t2k(
    const float* __restrict__ W2, const float* __restrict__ b2,
    const float* __restrict__ xsum, float* __restrict__ t2n)
{
    int b = blockIdx.y, n0 = blockIdx.x * 64;
    int w = threadIdx.x >> 6, lane = threadIdx.x & 63;
    const float* xs = xsum + b * E_;
    for (int nn = w; nn < 64; nn += 4) {
        int n = n0 + nn;
        const float* wr = W2 + (size_t)n * E_;
        float s = 0.f;
#pragma unroll
        for (int t = 0; t < 16; ++t) s = fmaf(wr[t * 64 + lane], xs[t * 64 + lane], s);
#pragma unroll
        for (int off = 1; off < 64; off <<= 1) s += __shfl_xor(s, off, 64);
        if (lane == 0) t2n[b * E_ + n] = s + 1024.0f * b2[n];
    }
}

// M[bh][a][c] = (1/8) * sum_d A[a][c][d] * t2[bh][d]
__global__ void compute_M(const float* __restrict__ A, const float* __restrict__ t2n,
                          float* __restrict__ Mout)
{
    int bh = blockIdx.x, b = bh >> 4, h = bh & 15;
    __shared__ float ts[64];
    if (threadIdx.x < 64) ts[threadIdx.x] = t2n[b * E_ + h * 64 + threadIdx.x];
    __syncthreads();
    int c = threadIdx.x & 63;
    int a0 = (threadIdx.x >> 6) * 16;
    for (int a = a0; a < a0 + 16; ++a) {
        float s = 0.f;
        const float* Ap = A + ((size_t)a * 64 + c) * 64;
#pragma unroll 8
        for (int d = 0; d < 64; ++d) s = fmaf(Ap[d], ts[d], s);
        Mout[((size_t)bh * 64 + a) * 64 + c] = s * 0.125f;
    }
}

// ---------------------------------------------------------------------------
// split-bf16 GEMM, 128x64 tile: C = X*W^T + bias (hi/lo, 3 MFMA products)
// mode 0: write fp32 heads layout (p0);  mode 1: write hi/lo bf16 heads (p1)
// 4 waves: waveM = w&1 (64 rows), waveN = w>>1 (32 cols). BK=32.
// ---------------------------------------------------------------------------
__global__ __launch_bounds__(256) void gemm_split128(
    const u16* __restrict__ Xh, const u16* __restrict__ Xl,
    const u16* __restrict__ Wh, const u16* __restrict__ Wl,
    const float* __restrict__ bias, float* __restrict__ outF,
    u16* __restrict__ oh, u16* __restrict__ ol, int mode)
{
    const int K = 1024;
    __shared__ __align__(16) u16 Xs_h[128 * 40];
    __shared__ __align__(16) u16 Xs_l[128 * 40];
    __shared__ __align__(16) u16 Ws_h[64 * 40];
    __shared__ __align__(16) u16 Ws_l[64 * 40];

    const int tid = threadIdx.x;
    const int w = tid >> 6, lane = tid & 63;
    const int waveM = w & 1, waveN = w >> 1;
    const int quad = lane >> 4, l16 = lane & 15;
    const int bm = blockIdx.x, bn = blockIdx.y;

    const int xrow = tid >> 1, xko = (tid & 1) * 16;   // X: 128 rows, 16 k each
    const int wrow = tid >> 2, wko = (tid & 3) * 8;    // W: 64 rows, 8 k each

    const u16* xh_g = Xh + (size_t)(bm * 128 + xrow) * K + xko;
    const u16* xl_g = Xl + (size_t)(bm * 128 + xrow) * K + xko;
    const u16* wh_g = Wh + (size_t)(bn * 64 + wrow) * K + wko;
    const u16* wl_g = Wl + (size_t)(bn * 64 + wrow) * K + wko;

    f32x4 acc[4][2] = {};

    for (int k0 = 0; k0 < K; k0 += 32) {
        uint4 xa = *(const uint4*)(xh_g + k0);
        uint4 xb = *(const uint4*)(xh_g + k0 + 8);
        uint4 xc = *(const uint4*)(xl_g + k0);
        uint4 xd = *(const uint4*)(xl_g + k0 + 8);
        uint4 wa = *(const uint4*)(wh_g + k0);
        uint4 wc = *(const uint4*)(wl_g + k0);
        __syncthreads();
        *(uint4*)&Xs_h[xrow * 40 + xko]     = xa;
        *(uint4*)&Xs_h[xrow * 40 + xko + 8] = xb;
        *(uint4*)&Xs_l[xrow * 40 + xko]     = xc;
        *(uint4*)&Xs_l[xrow * 40 + xko + 8] = xd;
        *(uint4*)&Ws_h[wrow * 40 + wko] = wa;
        *(uint4*)&Ws_l[wrow * 40 + wko] = wc;
        __syncthreads();

        short8 ah[4], al[4], bh_[2], bl_[2];
#pragma unroll
        for (int mt = 0; mt < 4; ++mt) {
            int r = (waveM * 64 + mt * 16 + l16) * 40 + quad * 8;
            ah[mt] = *(short8*)&Xs_h[r];
            al[mt] = *(short8*)&Xs_l[r];
        }
#pragma unroll
        for (int nt = 0; nt < 2; ++nt) {
            int r = (waveN * 32 + nt * 16 + l16) * 40 + quad * 8;
            bh_[nt] = *(short8*)&Ws_h[r];
            bl_[nt] = *(short8*)&Ws_l[r];
        }
#pragma unroll
        for (int mt = 0; mt < 4; ++mt)
#pragma unroll
            for (int nt = 0; nt < 2; ++nt) {
                acc[mt][nt] = __builtin_amdgcn_mfma_f32_16x16x32_bf16(ah[mt], bh_[nt], acc[mt][nt], 0, 0, 0);
                acc[mt][nt] = __builtin_amdgcn_mfma_f32_16x16x32_bf16(ah[mt], bl_[nt], acc[mt][nt], 0, 0, 0);
                acc[mt][nt] = __builtin_amdgcn_mfma_f32_16x16x32_bf16(al[mt], bh_[nt], acc[mt][nt], 0, 0, 0);
            }
    }

#pragma unroll
    for (int mt = 0; mt < 4; ++mt)
#pragma unroll
        for (int nt = 0; nt < 2; ++nt)
#pragma unroll
            for (int r = 0; r < 4; ++r) {
                int m = bm * 128 + waveM * 64 + mt * 16 + quad * 4 + r;
                int n = bn * 64 + waveN * 32 + nt * 16 + l16;
                float val = acc[mt][nt][r] + bias[n];
                int b = m >> 10, s = m & 1023, h = n >> 6, c = n & 63;
                size_t addr = ((size_t)(b * H_ + h) * S_ + s) * 64 + c;
                if (mode == 0) {
                    outF[addr] = val;
                } else {
                    u16 hh, ll; splitf(val, hh, ll);
                    oh[addr] = hh; ol[addr] = ll;
                }
            }
}

// q[bh][i][c] = sum_a p0[bh][i][a] * M[bh][a][c]; write hi/lo bf16
__global__ __launch_bounds__(256) void compute_q(
    const float* __restrict__ p0, const float* __restrict__ Min,
    u16* __restrict__ qh, u16* __restrict__ ql)
{
    int bh = blockIdx.y, i0 = blockIdx.x * 16;
    __shared__ float Ms[64 * 68];
    __shared__ float p0s[16 * 64];
    const float* base = p0 + ((size_t)bh * S_ + i0) * 64;
    for (int t = threadIdx.x; t < 4096; t += 256)
        Ms[(t >> 6) * 68 + (t & 63)] = Min[(size_t)bh * 4096 + t];
    for (int t = threadIdx.x; t < 1024; t += 256) p0s[t] = base[t];
    __syncthreads();
    int c = threadIdx.x & 63, il = threadIdx.x >> 6;
#pragma unroll
    for (int rr = 0; rr < 4; ++rr) {
        int ilocal = rr * 4 + il;
        const float* p0r = &p0s[ilocal * 64];
        float s = 0.f;
#pragma unroll 8
        for (int a = 0; a < 64; ++a) s = fmaf(p0r[a], Ms[a * 68 + c], s);
        size_t addr = ((size_t)bh * S_ + i0 + ilocal) * 64 + c;
        u16 hh, ll; splitf(s, hh, ll);
        qh[addr] = hh; ql[addr] = ll;
    }
}

// ---------------------------------------------------------------------------
// plain bf16 GEMM 64x64: X bf16 natural * W fp32 (cvt in staging) + bias
// mode 0: out bf16 TRANSPOSED heads layout vT[(bh*64 + d)*S + s]   (v)
// mode 1: out fp32 natural                                          (final)
// ---------------------------------------------------------------------------
__global__ __launch_bounds__(256) void gemm_plain(
    const u16* __restrict__ Xb, const float* __restrict__ Wf,
    const float* __restrict__ bias, u16* __restrict__ outB,
    float* __restrict__ outF, int mode)
{
    const int K = 1024;
    __shared__ __align__(16) u16 Xs[64 * 40];
    __shared__ __align__(16) u16 Ws[64 * 40];

    const int tid = threadIdx.x;
    const int w = tid >> 6, lane = tid & 63;
    const int waveM = w & 1, waveN = w >> 1;
    const int quad = lane >> 4, l16 = lane & 15;
    const int bm = blockIdx.x, bn = blockIdx.y;
    const int lrow = tid >> 2, lkoff = (tid & 3) * 8;

    const u16* xg = Xb + (size_t)(bm * 64 + lrow) * K + lkoff;
    const float* wg = Wf + (size_t)(bn * 64 + lrow) * K + lkoff;

    f32x4 acc[2][2] = {};

    for (int k0 = 0; k0 < K; k0 += 32) {
        uint4 xv = *(const uint4*)(xg + k0);
        float4 w0 = *(const float4*)(wg + k0);
        float4 w1 = *(const float4*)(wg + k0 + 4);
        short8 wp;
        ((u16*)&wp)[0] = f2b(w0.x); ((u16*)&wp)[1] = f2b(w0.y);
        ((u16*)&wp)[2] = f2b(w0.z); ((u16*)&wp)[3] = f2b(w0.w);
        ((u16*)&wp)[4] = f2b(w1.x); ((u16*)&wp)[5] = f2b(w1.y);
        ((u16*)&wp)[6] = f2b(w1.z); ((u16*)&wp)[7] = f2b(w1.w);
        __syncthreads();
        *(uint4*)&Xs[lrow * 40 + lkoff] = xv;
        *(short8*)&Ws[lrow * 40 + lkoff] = wp;
        __syncthreads();

        short8 af[2], bf_[2];
#pragma unroll
        for (int mt = 0; mt < 2; ++mt)
            af[mt] = *(short8*)&Xs[(waveM * 32 + mt * 16 + l16) * 40 + quad * 8];
#pragma unroll
        for (int nt = 0; nt < 2; ++nt)
            bf_[nt] = *(short8*)&Ws[(waveN * 32 + nt * 16 + l16) * 40 + quad * 8];
#pragma unroll
        for (int mt = 0; mt < 2; ++mt)
#pragma unroll
            for (int nt = 0; nt < 2; ++nt)
                acc[mt][nt] = __builtin_amdgcn_mfma_f32_16x16x32_bf16(af[mt], bf_[nt], acc[mt][nt], 0, 0, 0);
    }

#pragma unroll
    for (int mt = 0; mt < 2; ++mt)
#pragma unroll
        for (int nt = 0; nt < 2; ++nt)
#pragma unroll
            for (int r = 0; r < 4; ++r) {
                int m = bm * 64 + waveM * 32 + mt * 16 + quad * 4 + r;
                int n = bn * 64 + waveN * 32 + nt * 16 + l16;
                float val = acc[mt][nt][r] + bias[n];
                if (mode == 0) {
                    int b = m >> 10, s = m & 1023, h = n >> 6, c = n & 63;
                    outB[((size_t)((b * H_ + h) * 64 + c)) * S_ + s] = f2b(val);
                } else {
                    outF[(size_t)m * 1024 + n] = val;
                }
            }
}

// ---------------------------------------------------------------------------
// FUSED: logits = q*p1^T (split MFMA, round-6 verbatim), softmax, write fp32
// attn, then values = P @ v (MFMA; P via LDS with stride 72 — THE r5 fix).
// Block: 16 i-rows of one bh. Wave w: j-cols {64t + 16w + l16} for logits,
// d-col group [16w, 16w+16) for values.
// ---------------------------------------------------------------------------
__global__ __launch_bounds__(256) void logits_softmax_pv(
    const u16* __restrict__ qh, const u16* __restrict__ ql,
    const u16* __restrict__ p1h, const u16* __restrict__ p1l,
    const u16* __restrict__ vT, float* __restrict__ attn,
    u16* __restrict__ values)
{
    int bh = blockIdx.y, i0 = blockIdx.x * 16;
    int b = bh >> 4, h = bh & 15;
    int tid = threadIdx.x, w = tid >> 6, lane = tid & 63;
    int quad = lane >> 4, l16 = lane & 15;

    __shared__ __align__(16) u16 qhs[16 * 72], qls[16 * 72];
    __shared__ __align__(16) u16 p1hs[64 * 72], p1ls[64 * 72];
    __shared__ __align__(16) u16 Ps[16 * 72];     // stride 72 (r5 bug: was 40)
    __shared__ __align__(16) u16 vs_[64 * 72];
    __shared__ float redm[4][16], reds[4][16];

    {   // stage q (16x64 hi/lo)
        int row = tid >> 4, c0 = (tid & 15) * 4;
        size_t g = ((size_t)bh * S_ + i0 + row) * 64 + c0;
        *(us4*)&qhs[row * 72 + c0] = *(const us4*)&qh[g];
        *(us4*)&qls[row * 72 + c0] = *(const us4*)&ql[g];
    }
    __syncthreads();

    short8 ah[2], al[2];
#pragma unroll
    for (int ch = 0; ch < 2; ++ch) {
        ah[ch] = *(short8*)&qhs[l16 * 72 + ch * 32 + quad * 8];
        al[ch] = *(short8*)&qls[l16 * 72 + ch * 32 + quad * 8];
    }

    f32x4 L[16];
    for (int t = 0; t < 16; ++t) {
        __syncthreads();
        {   // stage p1 rows t*64 .. t*64+63 (hi/lo)
            int jl = tid >> 2, c0 = (tid & 3) * 16;
            size_t g = ((size_t)bh * S_ + t * 64 + jl) * 64 + c0;
            *(uint4*)&p1hs[jl * 72 + c0]     = *(const uint4*)&p1h[g];
            *(uint4*)&p1hs[jl * 72 + c0 + 8] = *(const uint4*)&p1h[g + 8];
            *(uint4*)&p1ls[jl * 72 + c0]     = *(const uint4*)&p1l[g];
            *(uint4*)&p1ls[jl * 72 + c0 + 8] = *(const uint4*)&p1l[g + 8];
        }
        __syncthreads();
        int jr = w * 16 + l16;
        short8 bh0 = *(short8*)&p1hs[jr * 72 + quad * 8];
        short8 bh1 = *(short8*)&p1hs[jr * 72 + 32 + quad * 8];
        short8 bl0 = *(short8*)&p1ls[jr * 72 + quad * 8];
        short8 bl1 = *(short8*)&p1ls[jr * 72 + 32 + quad * 8];
        f32x4 a = {};
        a = __builtin_amdgcn_mfma_f32_16x16x32_bf16(ah[0], bh0, a, 0, 0, 0);
        a = __builtin_amdgcn_mfma_f32_16x16x32_bf16(ah[1], bh1, a, 0, 0, 0);
        a = __builtin_amdgcn_mfma_f32_16x16x32_bf16(ah[0], bl0, a, 0, 0, 0);
        a = __builtin_amdgcn_mfma_f32_16x16x32_bf16(ah[1], bl1, a, 0, 0, 0);
        a = __builtin_amdgcn_mfma_f32_16x16x32_bf16(al[0], bh0, a, 0, 0, 0);
        a = __builtin_amdgcn_mfma_f32_16x16x32_bf16(al[1], bh1, a, 0, 0, 0);
        L[t] = a;
    }

    // softmax (round-6 verbatim)
    float mrow[4], srow[4];
#pragma unroll
    for (int r = 0; r < 4; ++r) {
        float m = L[0][r];
#pragma unroll
        for (int t = 1; t < 16; ++t) m = fmaxf(m, L[t][r]);
#pragma unroll
        for (int off = 1; off < 16; off <<= 1) m = fmaxf(m, __shfl_xor(m, off, 64));
        mrow[r] = m;
    }
    if (l16 == 0)
#pragma unroll
        for (int r = 0; r < 4; ++r) redm[w][quad * 4 + r] = mrow[r];
    __syncthreads();
#pragma unroll
    for (int r = 0; r < 4; ++r) {
        int row = quad * 4 + r;
        float m = fmaxf(fmaxf(redm[0][row], redm[1][row]), fmaxf(redm[2][row], redm[3][row]));
        float s = 0.f;
#pragma unroll
        for (int t = 0; t < 16; ++t) { L[t][r] = __expf(L[t][r] - m); s += L[t][r]; }
#pragma unroll
        for (int off = 1; off < 16; off <<= 1) s += __shfl_xor(s, off, 64);
        srow[r] = s;
    }
    if (l16 == 0)
#pragma unroll
        for (int r = 0; r < 4; ++r) reds[w][quad * 4 + r] = srow[r];
    __syncthreads();
#pragma unroll
    for (int r = 0; r < 4; ++r) {
        int row = quad * 4 + r;
        float inv = 1.0f / (reds[0][row] + reds[1][row] + reds[2][row] + reds[3][row]);
        float* arow = attn + ((size_t)bh * S_ + i0 + row) * S_;
#pragma unroll
        for (int t = 0; t < 16; ++t) {
            float p = L[t][r] * inv;
            L[t][r] = p;                          // keep normalized P for PV
            arow[t * 64 + w * 16 + l16] = p;
        }
    }

    // ---- PV: values[i][d] = sum_j P[i][j] * v[j][d] ----
    f32x4 acc_pv = {};
    for (int t = 0; t < 16; ++t) {
        __syncthreads();
        // P tile (16 x 64) from registers -> LDS, row stride 72
#pragma unroll
        for (int r = 0; r < 4; ++r)
            Ps[(quad * 4 + r) * 72 + w * 16 + l16] = f2b(L[t][r]);
        // v tile: vs_[d][j] direct bf16 copy from vT[(bh*64+d)*S + t*64 + j]
        {
            int d = tid >> 2, jc = (tid & 3) * 16;
            size_t g = ((size_t)(bh * 64 + d)) * S_ + t * 64 + jc;
            *(uint4*)&vs_[d * 72 + jc]     = *(const uint4*)&vT[g];
            *(uint4*)&vs_[d * 72 + jc + 8] = *(const uint4*)&vT[g + 8];
        }
        __syncthreads();
        int d = w * 16 + l16;
#pragma unroll
        for (int c0 = 0; c0 < 64; c0 += 32) {
            short8 af = *(short8*)&Ps[l16 * 72 + c0 + quad * 8];
            short8 bf = *(short8*)&vs_[d * 72 + c0 + quad * 8];
            acc_pv = __builtin_amdgcn_mfma_f32_16x16x32_bf16(af, bf, acc_pv, 0, 0, 0);
        }
    }
#pragma unroll
    for (int r = 0; r < 4; ++r) {
        int i = i0 + quad * 4 + r;
        int d = w * 16 + l16;
        values[((size_t)(b * S_ + i)) * E_ + h * 64 + d] = f2b(acc_pv[r]);
    }
}

extern "C" void kernel_launch(void* const* d_in, const int* in_sizes, int n_in,
                              void* d_out, int out_size, void* d_ws, size_t ws_size,
                              hipStream_t stream)
{
    const float* x  = (const float*)d_in[0];
    const float* W0 = (const float*)d_in[1];
    const float* b0 = (const float*)d_in[2];
    const float* W1 = (const float*)d_in[3];
    const float* b1 = (const float*)d_in[4];
    const float* W2 = (const float*)d_in[5];
    const float* b2 = (const float*)d_in[6];
    const float* Wv = (const float*)d_in[7];
    const float* bv = (const float*)d_in[8];
    const float* Wo = (const float*)d_in[9];
    const float* bo = (const float*)d_in[10];
    const float* A  = (const float*)d_in[11];

    float* out  = (float*)d_out;
    float* attn = out + (size_t)B_ * S_ * E_;

    // workspace (~88 MB; harness fill counters show d_ws >= 1 GB)
    u16* xh  = (u16*)d_ws;                  // 8 MB
    u16* xl  = xh + 4194304;                // 8 MB
    u16* w0h = xl + 4194304;                // 2 MB
    u16* w0l = w0h + 1048576;
    u16* w1h = w0l + 1048576;
    u16* w1l = w1h + 1048576;
    u16* p1h = w1l + 1048576;               // 8 MB
    u16* p1l = p1h + 4194304;               // 8 MB
    u16* qh  = p1l + 4194304;               // 8 MB
    u16* ql  = qh + 4194304;                // 8 MB
    u16* vT  = ql + 4194304;                // 8 MB (heads-transposed v)
    u16* values = vT + 4194304;             // 8 MB (bf16 natural)
    float* p0F  = (float*)(values + 4194304);  // 16 MB fp32 heads
    float* xsum = p0F + 4194304;            // 4096
    float* t2n  = xsum + 4096;              // 4096
    float* Mm   = t2n + 4096;               // 262144

    split_pair<<<4096, 256, 0, stream>>>(x, xh, xl, 1048576);
    split_pair<<<1024, 256, 0, stream>>>(W0, w0h, w0l, 262144);
    split_pair<<<1024, 256, 0, stream>>>(W1, w1h, w1l, 262144);
    reduce_xsum<<<dim3(4, 4), 256, 0, stream>>>(x, xsum);
    compute_t2k<<<dim3(16, 4), 256, 0, stream>>>(W2, b2, xsum, t2n);
    compute_M<<<BH_, 256, 0, stream>>>(A, t2n, Mm);

    dim3 gs(32, 16);
    gemm_split128<<<gs, 256, 0, stream>>>(xh, xl, w0h, w0l, b0, p0F, nullptr, nullptr, 0); // p0
    gemm_split128<<<gs, 256, 0, stream>>>(xh, xl, w1h, w1l, b1, nullptr, p1h, p1l, 1);     // p1

    dim3 gp(64, 16);
    gemm_plain<<<gp, 256, 0, stream>>>(xh, Wv, bv, vT, nullptr, 0);                        // vT

    compute_q<<<dim3(64, 64), 256, 0, stream>>>(p0F, Mm, qh, ql);

    logits_softmax_pv<<<dim3(64, 64), 256, 0, stream>>>(qh, ql, p1h, p1l, vT, attn, values);

    gemm_plain<<<gp, 256, 0, stream>>>(values, Wo, bo, nullptr, out, 1);
}

// Round 8
// 729.650 us; speedup vs baseline: 1.0511x; 1.0432x over previous
//
#include <hip/hip_runtime.h>
#include <hip/hip_bf16.h>
#include <cstddef>

#define B_ 4
#define S_ 1024
#define E_ 1024
#define H_ 16
#define D_ 64
#define BH_ (B_*H_)

typedef __attribute__((ext_vector_type(8))) short short8;    // 8 bf16
typedef __attribute__((ext_vector_type(4))) float f32x4;
typedef __attribute__((ext_vector_type(4))) unsigned short us4;
typedef unsigned short u16;

__device__ inline u16 f2b(float x) {
    return __builtin_bit_cast(u16, __float2bfloat16(x));
}
__device__ inline float b2f(u16 u) {
    return __bfloat162float(__builtin_bit_cast(__hip_bfloat16, u));
}
__device__ inline void splitf(float x, u16& h, u16& l) {
    h = f2b(x); l = f2b(x - b2f(h));
}

// ---------------------------------------------------------------------------
// split fp32 array into hi/lo bf16 arrays (n4 = n/4)
// ---------------------------------------------------------------------------
__global__ __launch_bounds__(256) void split_pair(
    const float* __restrict__ in, u16* __restrict__ oh, u16* __restrict__ ol, int n4)
{
    int i = blockIdx.x * 256 + threadIdx.x;
    if (i >= n4) return;
    float4 v = ((const float4*)in)[i];
    us4 h, l;
    splitf(v.x, ((u16*)&h)[0], ((u16*)&l)[0]);
    splitf(v.y, ((u16*)&h)[1], ((u16*)&l)[1]);
    splitf(v.z, ((u16*)&h)[2], ((u16*)&l)[2]);
    splitf(v.w, ((u16*)&h)[3], ((u16*)&l)[3]);
    ((us4*)oh)[i] = h;
    ((us4*)ol)[i] = l;
}

// xsum[b][k] = sum_s x[b,s,k]
__global__ __launch_bounds__(256) void reduce_xsum(
    const float* __restrict__ x, float* __restrict__ xsum)
{
    int b = blockIdx.y;
    int k = blockIdx.x * 256 + threadIdx.x;
    float s = 0.f;
    const float* base = x + (size_t)b * S_ * E_ + k;
    for (int j = 0; j < S_; ++j) s += base[(size_t)j * E_];
    xsum[b * E_ + k] = s;
}

// t2n[b][n] = dot(W2[n], xsum[b]) + S*b2[n]
__global__ __launch_bounds__(256) void compute_t2k(
    const float* __restrict__ W2, const float* __restrict__ b2,
    const float* __restrict__ xsum, float* __restrict__ t2n)
{
    int b = blockIdx.y, n0 = blockIdx.x * 64;
    int w = threadIdx.x >> 6, lane = threadIdx.x & 63;
    const float* xs = xsum + b * E_;
    for (int nn = w; nn < 64; nn += 4) {
        int n = n0 + nn;
        const float* wr = W2 + (size_t)n * E_;
        float s = 0.f;
#pragma unroll
        for (int t = 0; t < 16; ++t) s = fmaf(wr[t * 64 + lane], xs[t * 64 + lane], s);
#pragma unroll
        for (int off = 1; off < 64; off <<= 1) s += __shfl_xor(s, off, 64);
        if (lane == 0) t2n[b * E_ + n] = s + 1024.0f * b2[n];
    }
}

// M[bh][a][c] = (1/8) * sum_d A[a][c][d] * t2[bh][d]
__global__ void compute_M(const float* __restrict__ A, const float* __restrict__ t2n,
                          float* __restrict__ Mout)
{
    int bh = blockIdx.x, b = bh >> 4, h = bh & 15;
    __shared__ float ts[64];
    if (threadIdx.x < 64) ts[threadIdx.x] = t2n[b * E_ + h * 64 + threadIdx.x];
    __syncthreads();
    int c = threadIdx.x & 63;
    int a0 = (threadIdx.x >> 6) * 16;
    for (int a = a0; a < a0 + 16; ++a) {
        float s = 0.f;
        const float* Ap = A + ((size_t)a * 64 + c) * 64;
#pragma unroll 8
        for (int d = 0; d < 64; ++d) s = fmaf(Ap[d], ts[d], s);
        Mout[((size_t)bh * 64 + a) * 64 + c] = s * 0.125f;
    }
}

// ---------------------------------------------------------------------------
// split-bf16 GEMM, 128x64 tile (round-7 verbatim — PASSING)
// ---------------------------------------------------------------------------
__global__ __launch_bounds__(256) void gemm_split128(
    const u16* __restrict__ Xh, const u16* __restrict__ Xl,
    const u16* __restrict__ Wh, const u16* __restrict__ Wl,
    const float* __restrict__ bias, float* __restrict__ outF,
    u16* __restrict__ oh, u16* __restrict__ ol, int mode)
{
    const int K = 1024;
    __shared__ __align__(16) u16 Xs_h[128 * 40];
    __shared__ __align__(16) u16 Xs_l[128 * 40];
    __shared__ __align__(16) u16 Ws_h[64 * 40];
    __shared__ __align__(16) u16 Ws_l[64 * 40];

    const int tid = threadIdx.x;
    const int w = tid >> 6, lane = tid & 63;
    const int waveM = w & 1, waveN = w >> 1;
    const int quad = lane >> 4, l16 = lane & 15;
    const int bm = blockIdx.x, bn = blockIdx.y;

    const int xrow = tid >> 1, xko = (tid & 1) * 16;
    const int wrow = tid >> 2, wko = (tid & 3) * 8;

    const u16* xh_g = Xh + (size_t)(bm * 128 + xrow) * K + xko;
    const u16* xl_g = Xl + (size_t)(bm * 128 + xrow) * K + xko;
    const u16* wh_g = Wh + (size_t)(bn * 64 + wrow) * K + wko;
    const u16* wl_g = Wl + (size_t)(bn * 64 + wrow) * K + wko;

    f32x4 acc[4][2] = {};

    for (int k0 = 0; k0 < K; k0 += 32) {
        uint4 xa = *(const uint4*)(xh_g + k0);
        uint4 xb = *(const uint4*)(xh_g + k0 + 8);
        uint4 xc = *(const uint4*)(xl_g + k0);
        uint4 xd = *(const uint4*)(xl_g + k0 + 8);
        uint4 wa = *(const uint4*)(wh_g + k0);
        uint4 wc = *(const uint4*)(wl_g + k0);
        __syncthreads();
        *(uint4*)&Xs_h[xrow * 40 + xko]     = xa;
        *(uint4*)&Xs_h[xrow * 40 + xko + 8] = xb;
        *(uint4*)&Xs_l[xrow * 40 + xko]     = xc;
        *(uint4*)&Xs_l[xrow * 40 + xko + 8] = xd;
        *(uint4*)&Ws_h[wrow * 40 + wko] = wa;
        *(uint4*)&Ws_l[wrow * 40 + wko] = wc;
        __syncthreads();

        short8 ah[4], al[4], bh_[2], bl_[2];
#pragma unroll
        for (int mt = 0; mt < 4; ++mt) {
            int r = (waveM * 64 + mt * 16 + l16) * 40 + quad * 8;
            ah[mt] = *(short8*)&Xs_h[r];
            al[mt] = *(short8*)&Xs_l[r];
        }
#pragma unroll
        for (int nt = 0; nt < 2; ++nt) {
            int r = (waveN * 32 + nt * 16 + l16) * 40 + quad * 8;
            bh_[nt] = *(short8*)&Ws_h[r];
            bl_[nt] = *(short8*)&Ws_l[r];
        }
#pragma unroll
        for (int mt = 0; mt < 4; ++mt)
#pragma unroll
            for (int nt = 0; nt < 2; ++nt) {
                acc[mt][nt] = __builtin_amdgcn_mfma_f32_16x16x32_bf16(ah[mt], bh_[nt], acc[mt][nt], 0, 0, 0);
                acc[mt][nt] = __builtin_amdgcn_mfma_f32_16x16x32_bf16(ah[mt], bl_[nt], acc[mt][nt], 0, 0, 0);
                acc[mt][nt] = __builtin_amdgcn_mfma_f32_16x16x32_bf16(al[mt], bh_[nt], acc[mt][nt], 0, 0, 0);
            }
    }

#pragma unroll
    for (int mt = 0; mt < 4; ++mt)
#pragma unroll
        for (int nt = 0; nt < 2; ++nt)
#pragma unroll
            for (int r = 0; r < 4; ++r) {
                int m = bm * 128 + waveM * 64 + mt * 16 + quad * 4 + r;
                int n = bn * 64 + waveN * 32 + nt * 16 + l16;
                float val = acc[mt][nt][r] + bias[n];
                int b = m >> 10, s = m & 1023, h = n >> 6, c = n & 63;
                size_t addr = ((size_t)(b * H_ + h) * S_ + s) * 64 + c;
                if (mode == 0) {
                    outF[addr] = val;
                } else {
                    u16 hh, ll; splitf(val, hh, ll);
                    oh[addr] = hh; ol[addr] = ll;
                }
            }
}

// q[bh][i][c] = sum_a p0[bh][i][a] * M[bh][a][c]; write hi/lo bf16
__global__ __launch_bounds__(256) void compute_q(
    const float* __restrict__ p0, const float* __restrict__ Min,
    u16* __restrict__ qh, u16* __restrict__ ql)
{
    int bh = blockIdx.y, i0 = blockIdx.x * 16;
    __shared__ float Ms[64 * 68];
    __shared__ float p0s[16 * 64];
    const float* base = p0 + ((size_t)bh * S_ + i0) * 64;
    for (int t = threadIdx.x; t < 4096; t += 256)
        Ms[(t >> 6) * 68 + (t & 63)] = Min[(size_t)bh * 4096 + t];
    for (int t = threadIdx.x; t < 1024; t += 256) p0s[t] = base[t];
    __syncthreads();
    int c = threadIdx.x & 63, il = threadIdx.x >> 6;
#pragma unroll
    for (int rr = 0; rr < 4; ++rr) {
        int ilocal = rr * 4 + il;
        const float* p0r = &p0s[ilocal * 64];
        float s = 0.f;
#pragma unroll 8
        for (int a = 0; a < 64; ++a) s = fmaf(p0r[a], Ms[a * 68 + c], s);
        size_t addr = ((size_t)bh * S_ + i0 + ilocal) * 64 + c;
        u16 hh, ll; splitf(s, hh, ll);
        qh[addr] = hh; ql[addr] = ll;
    }
}

// ---------------------------------------------------------------------------
// plain bf16 GEMM 64x64 (round-7 verbatim — PASSING)
// mode 0: out bf16 TRANSPOSED heads layout vT[(bh*64 + d)*S + s]   (v)
// mode 1: out fp32 natural                                          (final)
// ---------------------------------------------------------------------------
__global__ __launch_bounds__(256) void gemm_plain(
    const u16* __restrict__ Xb, const float* __restrict__ Wf,
    const float* __restrict__ bias, u16* __restrict__ outB,
    float* __restrict__ outF, int mode)
{
    const int K = 1024;
    __shared__ __align__(16) u16 Xs[64 * 40];
    __shared__ __align__(16) u16 Ws[64 * 40];

    const int tid = threadIdx.x;
    const int w = tid >> 6, lane = tid & 63;
    const int waveM = w & 1, waveN = w >> 1;
    const int quad = lane >> 4, l16 = lane & 15;
    const int bm = blockIdx.x, bn = blockIdx.y;
    const int lrow = tid >> 2, lkoff = (tid & 3) * 8;

    const u16* xg = Xb + (size_t)(bm * 64 + lrow) * K + lkoff;
    const float* wg = Wf + (size_t)(bn * 64 + lrow) * K + lkoff;

    f32x4 acc[2][2] = {};

    for (int k0 = 0; k0 < K; k0 += 32) {
        uint4 xv = *(const uint4*)(xg + k0);
        float4 w0 = *(const float4*)(wg + k0);
        float4 w1 = *(const float4*)(wg + k0 + 4);
        short8 wp;
        ((u16*)&wp)[0] = f2b(w0.x); ((u16*)&wp)[1] = f2b(w0.y);
        ((u16*)&wp)[2] = f2b(w0.z); ((u16*)&wp)[3] = f2b(w0.w);
        ((u16*)&wp)[4] = f2b(w1.x); ((u16*)&wp)[5] = f2b(w1.y);
        ((u16*)&wp)[6] = f2b(w1.z); ((u16*)&wp)[7] = f2b(w1.w);
        __syncthreads();
        *(uint4*)&Xs[lrow * 40 + lkoff] = xv;
        *(short8*)&Ws[lrow * 40 + lkoff] = wp;
        __syncthreads();

        short8 af[2], bf_[2];
#pragma unroll
        for (int mt = 0; mt < 2; ++mt)
            af[mt] = *(short8*)&Xs[(waveM * 32 + mt * 16 + l16) * 40 + quad * 8];
#pragma unroll
        for (int nt = 0; nt < 2; ++nt)
            bf_[nt] = *(short8*)&Ws[(waveN * 32 + nt * 16 + l16) * 40 + quad * 8];
#pragma unroll
        for (int mt = 0; mt < 2; ++mt)
#pragma unroll
            for (int nt = 0; nt < 2; ++nt)
                acc[mt][nt] = __builtin_amdgcn_mfma_f32_16x16x32_bf16(af[mt], bf_[nt], acc[mt][nt], 0, 0, 0);
    }

#pragma unroll
    for (int mt = 0; mt < 2; ++mt)
#pragma unroll
        for (int nt = 0; nt < 2; ++nt)
#pragma unroll
            for (int r = 0; r < 4; ++r) {
                int m = bm * 64 + waveM * 32 + mt * 16 + quad * 4 + r;
                int n = bn * 64 + waveN * 32 + nt * 16 + l16;
                float val = acc[mt][nt][r] + bias[n];
                if (mode == 0) {
                    int b = m >> 10, s = m & 1023, h = n >> 6, c = n & 63;
                    outB[((size_t)((b * H_ + h) * 64 + c)) * S_ + s] = f2b(val);
                } else {
                    outF[(size_t)m * 1024 + n] = val;
                }
            }
}

// ---------------------------------------------------------------------------
// FUSED logits+softmax+PV, v2: 512 threads, 32 Q-rows/block, register
// prefetch of p1/v tiles (latency off the barrier path), nt attn stores.
// Wave w: wg = w>>2 row-group (16 rows), wj = w&3 j/d-quarter.
// ---------------------------------------------------------------------------
__global__ __launch_bounds__(512) void logits_softmax_pv(
    const u16* __restrict__ qh, const u16* __restrict__ ql,
    const u16* __restrict__ p1h, const u16* __restrict__ p1l,
    const u16* __restrict__ vT, float* __restrict__ attn,
    u16* __restrict__ values)
{
    int bh = blockIdx.y, i0 = blockIdx.x * 32;
    int b = bh >> 4, h = bh & 15;
    int tid = threadIdx.x, w = tid >> 6, lane = tid & 63;
    int quad = lane >> 4, l16 = lane & 15;
    int wg = w >> 2, wj = w & 3;

    __shared__ __align__(16) u16 qhs[32 * 72], qls[32 * 72];
    __shared__ __align__(16) u16 p1hs[64 * 72], p1ls[64 * 72];
    __shared__ __align__(16) u16 Ps[32 * 72];
    __shared__ __align__(16) u16 vs_[64 * 72];
    __shared__ float redm[4][32], reds[4][32];

    {   // stage q (32x64 hi/lo): 512 thr, row = tid>>4, c0 = (tid&15)*4
        int row = tid >> 4, c0 = (tid & 15) * 4;
        size_t g = ((size_t)bh * S_ + i0 + row) * 64 + c0;
        *(us4*)&qhs[row * 72 + c0] = *(const us4*)&qh[g];
        *(us4*)&qls[row * 72 + c0] = *(const us4*)&ql[g];
    }
    __syncthreads();

    short8 ah[2], al[2];
#pragma unroll
    for (int ch = 0; ch < 2; ++ch) {
        ah[ch] = *(short8*)&qhs[(wg * 16 + l16) * 72 + ch * 32 + quad * 8];
        al[ch] = *(short8*)&qls[(wg * 16 + l16) * 72 + ch * 32 + quad * 8];
    }

    // p1 staging indices (512 thr: one uint4 hi + one lo per thread)
    const int jl = tid >> 3, c0s = (tid & 7) * 8;
    size_t gp = ((size_t)bh * S_ + jl) * 64 + c0s;
    uint4 rh = *(const uint4*)&p1h[gp];
    uint4 rl = *(const uint4*)&p1l[gp];

    f32x4 L[16];
    for (int t = 0; t < 16; ++t) {
        __syncthreads();                          // prev tile fully consumed
        *(uint4*)&p1hs[jl * 72 + c0s] = rh;
        *(uint4*)&p1ls[jl * 72 + c0s] = rl;
        __syncthreads();
        if (t < 15) {                             // prefetch next (overlaps MFMA)
            size_t gn = gp + (size_t)(t + 1) * 64 * 64;
            rh = *(const uint4*)&p1h[gn];
            rl = *(const uint4*)&p1l[gn];
        }
        int jr = wj * 16 + l16;
        short8 bh0 = *(short8*)&p1hs[jr * 72 + quad * 8];
        short8 bh1 = *(short8*)&p1hs[jr * 72 + 32 + quad * 8];
        short8 bl0 = *(short8*)&p1ls[jr * 72 + quad * 8];
        short8 bl1 = *(short8*)&p1ls[jr * 72 + 32 + quad * 8];
        f32x4 a = {};
        a = __builtin_amdgcn_mfma_f32_16x16x32_bf16(ah[0], bh0, a, 0, 0, 0);
        a = __builtin_amdgcn_mfma_f32_16x16x32_bf16(ah[1], bh1, a, 0, 0, 0);
        a = __builtin_amdgcn_mfma_f32_16x16x32_bf16(ah[0], bl0, a, 0, 0, 0);
        a = __builtin_amdgcn_mfma_f32_16x16x32_bf16(ah[1], bl1, a, 0, 0, 0);
        a = __builtin_amdgcn_mfma_f32_16x16x32_bf16(al[0], bh0, a, 0, 0, 0);
        a = __builtin_amdgcn_mfma_f32_16x16x32_bf16(al[1], bh1, a, 0, 0, 0);
        L[t] = a;
    }

    // softmax: lane holds rows wg*16 + quad*4 + r, cols {64t + 16wj + l16}
    float mrow[4], srow[4];
#pragma unroll
    for (int r = 0; r < 4; ++r) {
        float m = L[0][r];
#pragma unroll
        for (int t = 1; t < 16; ++t) m = fmaxf(m, L[t][r]);
#pragma unroll
        for (int off = 1; off < 16; off <<= 1) m = fmaxf(m, __shfl_xor(m, off, 64));
        mrow[r] = m;
    }
    if (l16 == 0)
#pragma unroll
        for (int r = 0; r < 4; ++r) redm[wj][wg * 16 + quad * 4 + r] = mrow[r];
    __syncthreads();
#pragma unroll
    for (int r = 0; r < 4; ++r) {
        int rowg = wg * 16 + quad * 4 + r;
        float m = fmaxf(fmaxf(redm[0][rowg], redm[1][rowg]),
                        fmaxf(redm[2][rowg], redm[3][rowg]));
        float s = 0.f;
#pragma unroll
        for (int t = 0; t < 16; ++t) { L[t][r] = __expf(L[t][r] - m); s += L[t][r]; }
#pragma unroll
        for (int off = 1; off < 16; off <<= 1) s += __shfl_xor(s, off, 64);
        srow[r] = s;
    }
    if (l16 == 0)
#pragma unroll
        for (int r = 0; r < 4; ++r) reds[wj][wg * 16 + quad * 4 + r] = srow[r];
    __syncthreads();
#pragma unroll
    for (int r = 0; r < 4; ++r) {
        int rowg = wg * 16 + quad * 4 + r;
        float inv = 1.0f / (reds[0][rowg] + reds[1][rowg] + reds[2][rowg] + reds[3][rowg]);
        float* arow = attn + ((size_t)bh * S_ + i0 + rowg) * S_;
#pragma unroll
        for (int t = 0; t < 16; ++t) {
            float p = L[t][r] * inv;
            L[t][r] = p;                          // keep normalized P for PV
            __builtin_nontemporal_store(p, &arow[t * 64 + wj * 16 + l16]);
        }
    }

    // ---- PV: values[i][d] = sum_j P[i][j] * v[j][d] ----
    const int dv = tid >> 3, jc = (tid & 7) * 8;
    size_t gv = ((size_t)(bh * 64 + dv)) * S_ + jc;
    uint4 rv = *(const uint4*)&vT[gv];

    f32x4 acc_pv = {};
    for (int t = 0; t < 16; ++t) {
        __syncthreads();
        // P tile (32 x 64) regs -> LDS (stride 72)
#pragma unroll
        for (int r = 0; r < 4; ++r)
            Ps[(wg * 16 + quad * 4 + r) * 72 + wj * 16 + l16] = f2b(L[t][r]);
        *(uint4*)&vs_[dv * 72 + jc] = rv;
        __syncthreads();
        if (t < 15) rv = *(const uint4*)&vT[gv + (size_t)(t + 1) * 64];
        int d = wj * 16 + l16;
#pragma unroll
        for (int cc = 0; cc < 64; cc += 32) {
            short8 af = *(short8*)&Ps[(wg * 16 + l16) * 72 + cc + quad * 8];
            short8 bf = *(short8*)&vs_[d * 72 + cc + quad * 8];
            acc_pv = __builtin_amdgcn_mfma_f32_16x16x32_bf16(af, bf, acc_pv, 0, 0, 0);
        }
    }
#pragma unroll
    for (int r = 0; r < 4; ++r) {
        int i = i0 + wg * 16 + quad * 4 + r;
        int d = wj * 16 + l16;
        values[((size_t)(b * S_ + i)) * E_ + h * 64 + d] = f2b(acc_pv[r]);
    }
}

extern "C" void kernel_launch(void* const* d_in, const int* in_sizes, int n_in,
                              void* d_out, int out_size, void* d_ws, size_t ws_size,
                              hipStream_t stream)
{
    const float* x  = (const float*)d_in[0];
    const float* W0 = (const float*)d_in[1];
    const float* b0 = (const float*)d_in[2];
    const float* W1 = (const float*)d_in[3];
    const float* b1 = (const float*)d_in[4];
    const float* W2 = (const float*)d_in[5];
    const float* b2 = (const float*)d_in[6];
    const float* Wv = (const float*)d_in[7];
    const float* bv = (const float*)d_in[8];
    const float* Wo = (const float*)d_in[9];
    const float* bo = (const float*)d_in[10];
    const float* A  = (const float*)d_in[11];

    float* out  = (float*)d_out;
    float* attn = out + (size_t)B_ * S_ * E_;

    // workspace (~88 MB; harness fill counters show d_ws >= 1 GB)
    u16* xh  = (u16*)d_ws;                  // 8 MB
    u16* xl  = xh + 4194304;                // 8 MB
    u16* w0h = xl + 4194304;                // 2 MB
    u16* w0l = w0h + 1048576;
    u16* w1h = w0l + 1048576;
    u16* w1l = w1h + 1048576;
    u16* p1h = w1l + 1048576;               // 8 MB
    u16* p1l = p1h + 4194304;               // 8 MB
    u16* qh  = p1l + 4194304;               // 8 MB
    u16* ql  = qh + 4194304;                // 8 MB
    u16* vT  = ql + 4194304;                // 8 MB (heads-transposed v)
    u16* values = vT + 4194304;             // 8 MB (bf16 natural)
    float* p0F  = (float*)(values + 4194304);  // 16 MB fp32 heads
    float* xsum = p0F + 4194304;            // 4096
    float* t2n  = xsum + 4096;              // 4096
    float* Mm   = t2n + 4096;               // 262144

    split_pair<<<4096, 256, 0, stream>>>(x, xh, xl, 1048576);
    split_pair<<<1024, 256, 0, stream>>>(W0, w0h, w0l, 262144);
    split_pair<<<1024, 256, 0, stream>>>(W1, w1h, w1l, 262144);
    reduce_xsum<<<dim3(4, 4), 256, 0, stream>>>(x, xsum);
    compute_t2k<<<dim3(16, 4), 256, 0, stream>>>(W2, b2, xsum, t2n);
    compute_M<<<BH_, 256, 0, stream>>>(A, t2n, Mm);

    dim3 gs(32, 16);
    gemm_split128<<<gs, 256, 0, stream>>>(xh, xl, w0h, w0l, b0, p0F, nullptr, nullptr, 0); // p0
    gemm_split128<<<gs, 256, 0, stream>>>(xh, xl, w1h, w1l, b1, nullptr, p1h, p1l, 1);     // p1

    dim3 gp(64, 16);
    gemm_plain<<<gp, 256, 0, stream>>>(xh, Wv, bv, vT, nullptr, 0);                        // vT

    compute_q<<<dim3(64, 64), 256, 0, stream>>>(p0F, Mm, qh, ql);

    logits_softmax_pv<<<dim3(32, 64), 512, 0, stream>>>(qh, ql, p1h, p1l, vT, attn, values);

    gemm_plain<<<gp, 256, 0, stream>>>(values, Wo, bo, nullptr, out, 1);
}